// Round 8
// baseline (63.410 us; speedup 1.0000x reference)
//
#include <hip/hip_runtime.h>
#include <hip/hip_bf16.h>

// AlignConLoss: loss = sum_j [ log(sum_i exp(cn_i . an_j)) - cn_j . an_j ]
// (TEMPERATURE = 1; sim in [-1,1] so no LSE max-tracking needed)
// B = 8192, D = 256, inputs fp32, output: 1 fp32 scalar.
//
// R6 -> R7: gemm_colsum restructured to a counted-vmcnt pipeline (T3/T4
// mechanism, minimal form): double-buffered LDS, prefetch 2 K-tiles ahead,
// raw s_barrier + s_waitcnt vmcnt(8) instead of __syncthreads' vmcnt(0)
// drain. All fragments ds_read to registers before the buffer is released.
// MFMA shape / swizzle / staging addresses / epilogue unchanged from the
// verified R6 kernel.

#define BROWS 8192
#define DIM   256

typedef __bf16 bf16x8 __attribute__((ext_vector_type(8)));
typedef float  f32x4  __attribute__((ext_vector_type(4)));

__device__ __forceinline__ void gload_lds16(const void* g, void* l) {
  // 16B/lane async global->LDS; LDS dest is wave-uniform base + lane*16.
  __builtin_amdgcn_global_load_lds(
      (const __attribute__((address_space(1))) unsigned int*)g,
      (__attribute__((address_space(3))) unsigned int*)l, 16, 0, 0);
}

// ---------------------------------------------------------------------------
// Kernel 1: per-row L2 norms. Writes bf16-normalized An (embedding1/anchor)
// and Cn (embedding2/contrast); exact fp32 diag[r] = (a_r . c_r)/(|a_r||c_r|).
// One wave per row (D=256 -> float4 per lane). Also zeroes colsum[8192]
// (blocks 0..31) so no runtime memset is needed.
// ---------------------------------------------------------------------------
__global__ __launch_bounds__(256) void prep_kernel(
    const float* __restrict__ E1, const float* __restrict__ E2,
    __hip_bfloat16* __restrict__ An, __hip_bfloat16* __restrict__ Cn,
    float* __restrict__ diag, float* __restrict__ colsum) {
  if (blockIdx.x < 32) {
    colsum[blockIdx.x * 256 + threadIdx.x] = 0.f;
  }

  const int w    = threadIdx.x >> 6;
  const int lane = threadIdx.x & 63;
  const int row  = blockIdx.x * 4 + w;
  const size_t base = (size_t)row * DIM + lane * 4;

  const float4 a = *(const float4*)(E1 + base);
  const float4 c = *(const float4*)(E2 + base);

  float sa  = a.x*a.x + a.y*a.y + a.z*a.z + a.w*a.w;
  float sc  = c.x*c.x + c.y*c.y + c.z*c.z + c.w*c.w;
  float sac = a.x*c.x + a.y*c.y + a.z*c.z + a.w*c.w;
#pragma unroll
  for (int o = 32; o > 0; o >>= 1) {
    sa  += __shfl_down(sa,  o);
    sc  += __shfl_down(sc,  o);
    sac += __shfl_down(sac, o);
  }
  const float inva = 1.0f / fmaxf(sqrtf(__shfl(sa, 0)), 1e-8f);
  const float invc = 1.0f / fmaxf(sqrtf(__shfl(sc, 0)), 1e-8f);

  An[base + 0] = __float2bfloat16(a.x * inva);
  An[base + 1] = __float2bfloat16(a.y * inva);
  An[base + 2] = __float2bfloat16(a.z * inva);
  An[base + 3] = __float2bfloat16(a.w * inva);
  Cn[base + 0] = __float2bfloat16(c.x * invc);
  Cn[base + 1] = __float2bfloat16(c.y * invc);
  Cn[base + 2] = __float2bfloat16(c.z * invc);
  Cn[base + 3] = __float2bfloat16(c.w * invc);
  if (lane == 0) diag[row] = sac * inva * invc;
}

// ---------------------------------------------------------------------------
// Kernel 2: 128x128 sim tile, mfma_f32_16x16x32_bf16, counted-vmcnt pipeline.
//   prologue: STAGE(t0->buf0), STAGE(t1->buf1)                [16 vmem/wave]
//   iter t:   vmcnt(8) [t<3] / vmcnt(0) [t=3]  -> tile t landed, next in flight
//             raw barrier                      -> all waves see tile t
//             ds_read ALL frags -> regs; lgkmcnt(0); sched_barrier (rule #18)
//             raw barrier                      -> buf[t&1] fully consumed
//             STAGE(t+2 -> buf[t&1]) [t<2]     -> overwrite-safe by barrier
//             setprio(1); 32 MFMA; setprio(0)
// Race safety is local: loads into a buffer are only issued after a barrier
// that follows every wave's register-capture (lgkmcnt(0)) of that buffer.
// vmcnt counting: 8 loads/tile/wave, strict program order.
// Epilogue: exp + column reduce, one atomicAdd per column per block.
// ---------------------------------------------------------------------------
__global__ __launch_bounds__(256, 2) void gemm_colsum_kernel(
    const __hip_bfloat16* __restrict__ Cn,   // contrast rows -> sim rows i
    const __hip_bfloat16* __restrict__ An,   // anchor rows   -> sim cols j
    float* __restrict__ colsum) {
  __shared__ __align__(16) char ldsC[2][16384];   // [buf][128 rows][64 k] bf16
  __shared__ __align__(16) char ldsA[2][16384];
  __shared__ float ldscol[2][128];

  const int tid  = threadIdx.x;
  const int lane = tid & 63;
  const int w    = tid >> 6;      // 4 waves
  const int wr   = w >> 1;        // wave row (i) 0..1  -> 64 rows each
  const int wc   = w & 1;         // wave col (j) 0..1  -> 64 cols each

  const int jtile = blockIdx.x & 63;   // consecutive blocks share itile (L2)
  const int itile = blockIdx.x >> 6;
  const int i0 = itile * 128;
  const int j0 = jtile * 128;

  // staging geometry: call s covers rows s*32..s*32+31; thread -> (row, slot)
  const int rl  = tid >> 3;               // row within 32-row chunk
  const int kbl = (tid & 7) ^ (rl & 7);   // inverse-swizzled logical k-block
  const __hip_bfloat16* gC = Cn + (size_t)(i0 + rl) * DIM + kbl * 8;
  const __hip_bfloat16* gA = An + (size_t)(j0 + rl) * DIM + kbl * 8;

  auto stage = [&](int ks, int buf) {
    const int gk = ks * 64;
    char* lc = &ldsC[buf][0] + w * 1024;  // wave-uniform LDS base
    char* la = &ldsA[buf][0] + w * 1024;
#pragma unroll
    for (int s = 0; s < 4; ++s) {
      gload_lds16(gC + (size_t)s * 32 * DIM + gk, lc + s * 4096);
      gload_lds16(gA + (size_t)s * 32 * DIM + gk, la + s * 4096);
    }
  };

  f32x4 acc[4][4] = {};

  stage(0, 0);                            // prologue: 2 tiles in flight
  stage(1, 1);

  const int q     = lane >> 4;
  const int sw    = lane & 7;
  const int rbase = lane & 15;

#pragma unroll
  for (int t = 0; t < 4; ++t) {           // K = 256 = 4 * BK(64)
    const int b = t & 1;
    if (t < 3) { asm volatile("s_waitcnt vmcnt(8)" ::: "memory"); }
    else       { asm volatile("s_waitcnt vmcnt(0)" ::: "memory"); }
    __builtin_amdgcn_sched_barrier(0);
    __builtin_amdgcn_s_barrier();         // tile t visible to all waves

    bf16x8 af[2][4], bfv[2][4];
#pragma unroll
    for (int kk = 0; kk < 2; ++kk) {      // capture ALL frags to registers
      const int slot = (q + kk * 4) ^ sw; // undo source swizzle
#pragma unroll
      for (int m = 0; m < 4; ++m) {
        const int r = wr * 64 + m * 16 + rbase;
        af[kk][m] = *(const bf16x8*)(&ldsC[b][0] + r * 128 + slot * 16);
      }
#pragma unroll
      for (int n = 0; n < 4; ++n) {
        const int r = wc * 64 + n * 16 + rbase;
        bfv[kk][n] = *(const bf16x8*)(&ldsA[b][0] + r * 128 + slot * 16);
      }
    }
    asm volatile("s_waitcnt lgkmcnt(0)" ::: "memory");
    __builtin_amdgcn_sched_barrier(0);    // rule #18: fence MFMA hoist
    __builtin_amdgcn_s_barrier();         // buf b fully consumed by all waves
    __builtin_amdgcn_sched_barrier(0);

    if (t < 2) stage(t + 2, b);           // prefetch 2 ahead into freed buf
    __builtin_amdgcn_sched_barrier(0);

    __builtin_amdgcn_s_setprio(1);
#pragma unroll
    for (int kk = 0; kk < 2; ++kk)
#pragma unroll
      for (int m = 0; m < 4; ++m)
#pragma unroll
        for (int n = 0; n < 4; ++n)
          acc[m][n] = __builtin_amdgcn_mfma_f32_16x16x32_bf16(
              af[kk][m], bfv[kk][n], acc[m][n], 0, 0, 0);
    __builtin_amdgcn_s_setprio(0);
  }

  // Epilogue: colpart[j] = sum over this block's 128 i-rows of exp(sim).
  // C/D layout (m89-verified): col = lane&15, row = (lane>>4)*4 + reg.
#pragma unroll
  for (int n = 0; n < 4; ++n) {
    float s = 0.f;
#pragma unroll
    for (int m = 0; m < 4; ++m) {
      const f32x4 v = acc[m][n];
      s += __expf(v[0]) + __expf(v[1]) + __expf(v[2]) + __expf(v[3]);
    }
    s += __shfl_xor(s, 16);   // combine the 4 row-groups sharing lane&15
    s += __shfl_xor(s, 32);
    if (lane < 16) ldscol[wr][wc * 64 + n * 16 + lane] = s;
  }
  __syncthreads();
  if (tid < 128) {
    const float v = ldscol[0][tid] + ldscol[1][tid];
    atomicAdd(&colsum[j0 + tid], v);
  }
}

// ---------------------------------------------------------------------------
// Kernel 3: loss = sum_j log(colsum[j]) - diag[j].  Single block.
// ---------------------------------------------------------------------------
__global__ __launch_bounds__(256) void finalize_kernel(
    const float* __restrict__ colsum, const float* __restrict__ diag,
    float* __restrict__ out) {
  const int t = threadIdx.x;
  float s = 0.f;
  for (int j = t; j < BROWS; j += 256) s += logf(colsum[j]) - diag[j];
#pragma unroll
  for (int o = 32; o > 0; o >>= 1) s += __shfl_down(s, o);
  __shared__ float red[4];
  if ((t & 63) == 0) red[t >> 6] = s;
  __syncthreads();
  if (t == 0) out[0] = red[0] + red[1] + red[2] + red[3];
}

// ---------------------------------------------------------------------------
// ws layout (needs ~8.07 MB):
//   [0, 4MiB)          Cn bf16 [8192*256]
//   [4MiB, 8MiB)       An bf16 [8192*256]
//   [8MiB, +32KiB)     colsum f32 [8192]
//   [8MiB+32K, +32KiB) diag   f32 [8192]
// ---------------------------------------------------------------------------
extern "C" void kernel_launch(void* const* d_in, const int* in_sizes, int n_in,
                              void* d_out, int out_size, void* d_ws, size_t ws_size,
                              hipStream_t stream) {
  const float* E1 = (const float*)d_in[0];   // encoder_embedding1 -> anchors
  const float* E2 = (const float*)d_in[1];   // encoder_embedding2 -> contrast
  char* ws = (char*)d_ws;
  __hip_bfloat16* Cn = (__hip_bfloat16*)(ws);
  __hip_bfloat16* An = (__hip_bfloat16*)(ws + (size_t)4 * 1024 * 1024);
  float* colsum = (float*)(ws + (size_t)8 * 1024 * 1024);
  float* diag   = (float*)(ws + (size_t)8 * 1024 * 1024 + 32 * 1024);
  float* out = (float*)d_out;

  prep_kernel<<<BROWS / 4, 256, 0, stream>>>(E1, E2, An, Cn, diag, colsum);
  gemm_colsum_kernel<<<(BROWS / 128) * (BROWS / 128), 256, 0, stream>>>(Cn, An, colsum);
  finalize_kernel<<<1, 256, 0, stream>>>(colsum, diag, out);
}

// Round 9
// 48.942 us; speedup vs baseline: 1.2956x; 1.2956x over previous
//
#include <hip/hip_runtime.h>
#include <hip/hip_bf16.h>
#include <hip/hip_fp8.h>

// AlignConLoss: loss = sum_j [ log(sum_i exp(cn_i . an_j)) - cn_j . an_j ]
// B = 8192, D = 256, fp32 inputs, scalar fp32 out. sim in [-1,1] -> no max.
//
// R8 -> R9: operands quantized to fp8 e4m3 (OCP). Non-scaled
// mfma_f32_16x16x32_fp8_fp8 runs at bf16 rate, but LDS traffic, L2 traffic,
// and staging all HALVE — those were the binding pipes (R8: occupancy 17.7%,
// MfmaUtil 27%). fp8 dbuf tile = 33 KB LDS -> 4 blocks/CU (occupancy 2x vs
// R8) while keeping the counted-vmcnt pipeline. diag stays exact fp32.

#define BROWS 8192
#define DIM   256

typedef float f32x4 __attribute__((ext_vector_type(4)));

__device__ __forceinline__ void gload_lds16(const void* g, void* l) {
  __builtin_amdgcn_global_load_lds(
      (const __attribute__((address_space(1))) unsigned int*)g,
      (__attribute__((address_space(3))) unsigned int*)l, 16, 0, 0);
}

__device__ __forceinline__ unsigned char to_e4m3(float v) {
  __hip_fp8_e4m3 t(v);
  return *reinterpret_cast<unsigned char*>(&t);
}

// ---------------------------------------------------------------------------
// Kernel 1: per-row L2 norms -> fp8 e4m3 normalized An/Cn; exact fp32 diag.
// One wave per row. Blocks 0..31 also zero colsum[8192].
// ---------------------------------------------------------------------------
__global__ __launch_bounds__(256) void prep_kernel(
    const float* __restrict__ E1, const float* __restrict__ E2,
    unsigned char* __restrict__ An8, unsigned char* __restrict__ Cn8,
    float* __restrict__ diag, float* __restrict__ colsum) {
  if (blockIdx.x < 32) colsum[blockIdx.x * 256 + threadIdx.x] = 0.f;

  const int w    = threadIdx.x >> 6;
  const int lane = threadIdx.x & 63;
  const int row  = blockIdx.x * 4 + w;
  const size_t base = (size_t)row * DIM + lane * 4;

  const float4 a = *(const float4*)(E1 + base);
  const float4 c = *(const float4*)(E2 + base);

  float sa  = a.x*a.x + a.y*a.y + a.z*a.z + a.w*a.w;
  float sc  = c.x*c.x + c.y*c.y + c.z*c.z + c.w*c.w;
  float sac = a.x*c.x + a.y*c.y + a.z*c.z + a.w*c.w;
#pragma unroll
  for (int o = 32; o > 0; o >>= 1) {
    sa  += __shfl_down(sa,  o);
    sc  += __shfl_down(sc,  o);
    sac += __shfl_down(sac, o);
  }
  const float inva = 1.0f / fmaxf(sqrtf(__shfl(sa, 0)), 1e-8f);
  const float invc = 1.0f / fmaxf(sqrtf(__shfl(sc, 0)), 1e-8f);

  uchar4 pa, pc;
  pa.x = to_e4m3(a.x * inva); pa.y = to_e4m3(a.y * inva);
  pa.z = to_e4m3(a.z * inva); pa.w = to_e4m3(a.w * inva);
  pc.x = to_e4m3(c.x * invc); pc.y = to_e4m3(c.y * invc);
  pc.z = to_e4m3(c.z * invc); pc.w = to_e4m3(c.w * invc);
  *(uchar4*)(An8 + base) = pa;
  *(uchar4*)(Cn8 + base) = pc;
  if (lane == 0) diag[row] = sac * inva * invc;
}

// ---------------------------------------------------------------------------
// Kernel 2: 128x128 sim tile, mfma_f32_16x16x32_fp8_fp8 (i64 A/B operands),
// counted-vmcnt dbuf pipeline (R7 sync structure, proven-correct), fp8 tiles:
//   LDS tile/matrix = 128 rows x 64 B; dbuf x 2 matrices = 32 KB (+1 KB epi)
//   -> 4 blocks/CU. 4 gloads/wave/stage -> steady s_waitcnt vmcnt(4).
// Swizzle (rule #21, both-sides involution): 16B-block p_phys = p_log ^
// ((row>>1)&3). Stage source: lane l covers row (l>>2), phys block (l&3) ->
// logical block (l&3)^((l>>3)&3) (lane-pure). ds_read b64: chunk c=kk*4+q,
// addr = r*64 + ((c>>1)^rsw)*16 + (c&1)*8, rsw = ((lane&15)>>1)&3.
// K-chunk permutation identical for A and B -> cancels in the dot product.
// ---------------------------------------------------------------------------
__global__ __launch_bounds__(256, 4) void gemm_colsum_kernel(
    const unsigned char* __restrict__ Cn8,   // contrast rows -> sim rows i
    const unsigned char* __restrict__ An8,   // anchor rows   -> sim cols j
    float* __restrict__ colsum) {
  __shared__ __align__(16) char ldsC[2][8192];   // [buf][128 rows][64 B]
  __shared__ __align__(16) char ldsA[2][8192];
  __shared__ float ldscol[2][128];

  const int tid  = threadIdx.x;
  const int lane = tid & 63;
  const int w    = tid >> 6;      // 4 waves
  const int wr   = w >> 1;        // wave row (i) 0..1 -> 64 rows
  const int wc   = w & 1;         // wave col (j) 0..1 -> 64 cols

  const int jtile = blockIdx.x & 63;   // consecutive blocks share itile (L2)
  const int itile = blockIdx.x >> 6;
  const int i0 = itile * 128;
  const int j0 = jtile * 128;

  // staging: wave w, call j covers rows w*32+j*16+(l>>2); 16B = one block.
  const int srow = w * 32 + (lane >> 2);
  const int sblk = (lane & 3) ^ ((lane >> 3) & 3);   // logical 16B block
  const unsigned char* gC = Cn8 + (size_t)(i0 + srow) * DIM + sblk * 16;
  const unsigned char* gA = An8 + (size_t)(j0 + srow) * DIM + sblk * 16;
  char* lbC0 = &ldsC[0][0] + w * 2048;
  char* lbA0 = &ldsA[0][0] + w * 2048;

  auto stage = [&](int ks, int buf) {
    const int gk = ks * 64;
    char* lc = lbC0 + buf * 8192;
    char* la = lbA0 + buf * 8192;
#pragma unroll
    for (int j = 0; j < 2; ++j) {
      gload_lds16(gC + (size_t)j * 16 * DIM + gk, lc + j * 1024);
      gload_lds16(gA + (size_t)j * 16 * DIM + gk, la + j * 1024);
    }
  };

  f32x4 acc[4][4] = {};

  stage(0, 0);                          // prologue: 2 tiles in flight (8 vmem)
  stage(1, 1);

  const int q     = lane >> 4;                 // k-chunk within K=32 window
  const int rsw   = ((lane & 15) >> 1) & 3;    // row swizzle bits
  const int rbase = lane & 15;

#pragma unroll
  for (int t = 0; t < 4; ++t) {         // K = 256 = 4 * BK(64)
    const int b = t & 1;
    if (t < 3) { asm volatile("s_waitcnt vmcnt(4)" ::: "memory"); }
    else       { asm volatile("s_waitcnt vmcnt(0)" ::: "memory"); }
    __builtin_amdgcn_sched_barrier(0);
    __builtin_amdgcn_s_barrier();       // tile t visible to all waves

    long long af[2][4], bfv[2][4];
#pragma unroll
    for (int kk = 0; kk < 2; ++kk) {    // capture ALL frags to registers
      const int c    = kk * 4 + q;
      const int boff = (((c >> 1) ^ rsw) << 4) + ((c & 1) << 3);
#pragma unroll
      for (int m = 0; m < 4; ++m) {
        const int r = wr * 64 + m * 16 + rbase;
        af[kk][m] = *(const long long*)(&ldsC[b][0] + r * 64 + boff);
      }
#pragma unroll
      for (int n = 0; n < 4; ++n) {
        const int r = wc * 64 + n * 16 + rbase;
        bfv[kk][n] = *(const long long*)(&ldsA[b][0] + r * 64 + boff);
      }
    }
    asm volatile("s_waitcnt lgkmcnt(0)" ::: "memory");
    __builtin_amdgcn_sched_barrier(0);  // rule #18: fence MFMA hoist
    __builtin_amdgcn_s_barrier();       // buf b fully consumed by all waves
    __builtin_amdgcn_sched_barrier(0);

    if (t < 2) stage(t + 2, b);         // prefetch 2 ahead into freed buf
    __builtin_amdgcn_sched_barrier(0);

    __builtin_amdgcn_s_setprio(1);
#pragma unroll
    for (int kk = 0; kk < 2; ++kk)
#pragma unroll
      for (int m = 0; m < 4; ++m)
#pragma unroll
        for (int n = 0; n < 4; ++n)
          acc[m][n] = __builtin_amdgcn_mfma_f32_16x16x32_fp8_fp8(
              af[kk][m], bfv[kk][n], acc[m][n], 0, 0, 0);
    __builtin_amdgcn_s_setprio(0);
  }

  // Epilogue: colpart[j] = sum over this block's 128 i-rows of exp(sim).
  // C/D layout (m89; dtype-independent m121): col = lane&15, row=(lane>>4)*4+reg.
#pragma unroll
  for (int n = 0; n < 4; ++n) {
    float s = 0.f;
#pragma unroll
    for (int m = 0; m < 4; ++m) {
      const f32x4 v = acc[m][n];
      s += __expf(v[0]) + __expf(v[1]) + __expf(v[2]) + __expf(v[3]);
    }
    s += __shfl_xor(s, 16);
    s += __shfl_xor(s, 32);
    if (lane < 16) ldscol[wr][wc * 64 + n * 16 + lane] = s;
  }
  __syncthreads();
  if (tid < 128) {
    const float v = ldscol[0][tid] + ldscol[1][tid];
    atomicAdd(&colsum[j0 + tid], v);
  }
}

// ---------------------------------------------------------------------------
// Kernel 3: loss = sum_j log(colsum[j]) - diag[j].  Single block.
// ---------------------------------------------------------------------------
__global__ __launch_bounds__(256) void finalize_kernel(
    const float* __restrict__ colsum, const float* __restrict__ diag,
    float* __restrict__ out) {
  const int t = threadIdx.x;
  float s = 0.f;
  for (int j = t; j < BROWS; j += 256) s += logf(colsum[j]) - diag[j];
#pragma unroll
  for (int o = 32; o > 0; o >>= 1) s += __shfl_down(s, o);
  __shared__ float red[4];
  if ((t & 63) == 0) red[t >> 6] = s;
  __syncthreads();
  if (t == 0) out[0] = red[0] + red[1] + red[2] + red[3];
}

// ---------------------------------------------------------------------------
// ws layout (~4.07 MB):
//   [0, 2MiB)            Cn8 fp8 [8192*256]
//   [2MiB, 4MiB)         An8 fp8 [8192*256]
//   [4MiB, +32KiB)       colsum f32 [8192]
//   [4MiB+32K, +32KiB)   diag   f32 [8192]
// ---------------------------------------------------------------------------
extern "C" void kernel_launch(void* const* d_in, const int* in_sizes, int n_in,
                              void* d_out, int out_size, void* d_ws, size_t ws_size,
                              hipStream_t stream) {
  const float* E1 = (const float*)d_in[0];   // encoder_embedding1 -> anchors
  const float* E2 = (const float*)d_in[1];   // encoder_embedding2 -> contrast
  char* ws = (char*)d_ws;
  unsigned char* Cn8 = (unsigned char*)(ws);
  unsigned char* An8 = (unsigned char*)(ws + (size_t)2 * 1024 * 1024);
  float* colsum = (float*)(ws + (size_t)4 * 1024 * 1024);
  float* diag   = (float*)(ws + (size_t)4 * 1024 * 1024 + 32 * 1024);
  float* out = (float*)d_out;

  prep_kernel<<<BROWS / 4, 256, 0, stream>>>(E1, E2, An8, Cn8, diag, colsum);
  gemm_colsum_kernel<<<(BROWS / 128) * (BROWS / 128), 256, 0, stream>>>(Cn8, An8, colsum);
  finalize_kernel<<<1, 256, 0, stream>>>(colsum, diag, out);
}